// Round 10
// baseline (650.966 us; speedup 1.0000x reference)
//
#include <hip/hip_runtime.h>
#include <math.h>

#define NB    8
#define IMG   224
#define NTOK  (IMG*IMG)          // 50176 per batch
#define DIM   96
#define INR   128
#define HIDN  384
#define WT    49
#define SCALE 0.17677669529663687f
#define OSS   136                // os row stride (shorts)
#define TSS   132                // ts row stride (shorts)

typedef __attribute__((ext_vector_type(8))) short bf16x8;
typedef __attribute__((ext_vector_type(4))) float f32x4;
typedef __attribute__((ext_vector_type(4))) unsigned int u32x4;

#define MFMA16(a,b,c) __builtin_amdgcn_mfma_f32_16x16x32_bf16((a),(b),(c),0,0,0)

__device__ __forceinline__ short f2bf(float f) {
    unsigned u = __builtin_bit_cast(unsigned, f);
    u += 0x7fffu + ((u >> 16) & 1u);
    return (short)(u >> 16);
}

// truncating pack of two f32 -> packed bf16x2 (lo in low 16)
__device__ __forceinline__ unsigned pktrunc(float lo, float hi) {
    return (__builtin_bit_cast(unsigned, hi) & 0xFFFF0000u) |
           (__builtin_bit_cast(unsigned, lo) >> 16);
}

// tanh-form GELU
__device__ __forceinline__ float gelu_f(float z) {
    const float u = z * 1.5957691216057308f * fmaf(0.044715f * z, z, 1.f);
    return z / (1.f + __expf(-u));
}

// ---------- prep: convert weights to bf16, gather rel bias (pre-scaled, padded [4][49][64]) ----------
__global__ void prep_kernel(const float* __restrict__ wqkv, const float* __restrict__ wout,
                            const float* __restrict__ w1,   const float* __restrict__ w2,
                            const float* __restrict__ rel_bias, char* __restrict__ ws)
{
    short* wqkvb = (short*)ws;                 // 36864 elems
    short* woutb = (short*)(ws + 73728);       // 12288
    short* w1b   = (short*)(ws + 98304);       // 36864
    short* w2b   = (short*)(ws + 172032);      // 36864
    float* biasp = (float*)(ws + 245760);      // [4][49][64] fp32, pre-scaled, key-padded
    const int idx = blockIdx.x * 256 + threadIdx.x;
    if      (idx < 36864)  wqkvb[idx]          = f2bf(wqkv[idx]);
    else if (idx < 49152)  woutb[idx - 36864]  = f2bf(wout[idx - 36864]);
    else if (idx < 86016)  w1b[idx - 49152]    = f2bf(w1[idx - 49152]);
    else if (idx < 122880) w2b[idx - 86016]    = f2bf(w2[idx - 86016]);
    else if (idx < 135424) {
        const int t = idx - 122880;
        const int h = t / 3136, r = t % 3136, q = r / 64, k = r % 64;
        float v = 0.f;
        if (k < 49) {
            const int rel = (q/7 - k/7 + 6) * 13 + (q%7 - k%7 + 6);
            v = rel_bias[rel * 4 + h] * SCALE;
        }
        biasp[t] = v;
    }
}

// ---------- fused kernel: LN1+qkv+attn+proj+LN2+FFN, one block = one 7x7 window ----------
// LDS pool = 32768 B exactly -> 5 blocks/CU (160 KiB). Staged aliasing:
//   stage A: hs[64][104]                 [0,13312)
//   stage B: qk[4 heads][64 rows][64c]   [0,32768)   XOR-swizzled, stride 128 B/row
//            (byte ^= (row&7)<<4 on BOTH store and read: stride-64 alone = 16-way conflict)
//   stage C: os[64][OSS]                 [0,17408)   (aliases qk;  barrier b3)
//   stage D: h2[64][104]                 [0,13312)   (aliases os;  barrier b5)
//            ts[64][TSS]                 [13312,30208)   (FFN 128-col chunk)
__global__ __launch_bounds__(256, 3) void fused_kernel(
    const float* __restrict__ x, const char* __restrict__ ws,
    const float* __restrict__ b_out, const float* __restrict__ ln1_g,
    const float* __restrict__ ln1_b, const float* __restrict__ ln2_g,
    const float* __restrict__ ln2_b, const float* __restrict__ b1,
    const float* __restrict__ b2, float* __restrict__ y)
{
    __shared__ __align__(16) char pool[32768];
    short* hs = (short*)pool;
    short* os = (short*)pool;
    short* h2 = (short*)pool;
    short* ts = (short*)(pool + 13312);

    const short* wqkvb = (const short*)ws;
    const short* woutb = (const short*)(ws + 73728);
    const short* w1b   = (const short*)(ws + 98304);
    const short* w2b   = (const short*)(ws + 172032);
    const float* biasp = (const float*)(ws + 245760);

    const int tid = threadIdx.x;
    const int wv  = tid >> 6;         // wave = head (attn) / M-tile (proj,FFN)
    const int l15 = tid & 15;
    const int l4  = (tid & 63) >> 4;
    const int wid = blockIdx.x;
    const int b = wid >> 10, xr = (wid >> 5) & 31, yr = wid & 31;
    char* qkb = pool + wv * 8192;     // this head's swizzled q|k region

    // ---- LN1: 4 threads per row ----
    if (tid < 196) {
        const int i = tid >> 2, g = tid & 3;
        const float* xp = x + ((size_t)b * NTOK + (size_t)(xr*7 + i/7) * IMG + (yr*7 + i%7)) * DIM + g*24;
        float v[24]; float s = 0.f, s2 = 0.f;
        #pragma unroll
        for (int c = 0; c < 6; ++c) {
            const float4 t4 = *reinterpret_cast<const float4*>(xp + c*4);
            v[c*4+0]=t4.x; v[c*4+1]=t4.y; v[c*4+2]=t4.z; v[c*4+3]=t4.w;
            s  += t4.x + t4.y + t4.z + t4.w;
            s2 += t4.x*t4.x + t4.y*t4.y + t4.z*t4.z + t4.w*t4.w;
        }
        s  += __shfl_xor(s, 1);  s  += __shfl_xor(s, 2);
        s2 += __shfl_xor(s2, 1); s2 += __shfl_xor(s2, 2);
        const float mu = s * (1.f/96.f);
        const float rs = rsqrtf(s2 * (1.f/96.f) - mu*mu + 1e-5f);
        #pragma unroll
        for (int c = 0; c < 24; ++c) {
            const int d = g*24 + c;
            hs[i*104 + d] = f2bf((v[c] - mu) * rs * ln1_g[d] + ln1_b[d]);
        }
    }
    for (int idx = tid; idx < 15*104; idx += 256) hs[49*104 + idx] = 0;
    __syncthreads();   // b1: hs ready

    // ---- qkv GEMM, head-partitioned: wave wv computes its own head's q,k,v ----
    u32x4 vfrag[2][2];   // V packed bf16, PV A-operand (regs only)
    {
        f32x4 acc[6][4];
        #pragma unroll
        for (int nt = 0; nt < 6; ++nt)
            #pragma unroll
            for (int mt = 0; mt < 4; ++mt)
                acc[nt][mt] = (f32x4){0.f,0.f,0.f,0.f};
        // k3-outer: A-frags 16 regs at a time
        #pragma unroll
        for (int k3 = 0; k3 < 3; ++k3) {
            bf16x8 a4[4];
            #pragma unroll
            for (int mt = 0; mt < 4; ++mt)
                a4[mt] = *reinterpret_cast<const bf16x8*>(&hs[(mt*16 + l15)*104 + k3*32 + l4*8]);
            #pragma unroll
            for (int nt = 0; nt < 6; ++nt) {
                const int wrow = (nt < 2 ? wv*32 + nt*16
                                 : nt < 4 ? 128 + wv*32 + (nt-2)*16
                                          : 256 + wv*32 + (nt-4)*16);
                const bf16x8 bfr = *reinterpret_cast<const bf16x8*>(
                    wqkvb + (size_t)(wrow + l15)*96 + k3*32 + l4*8);
                #pragma unroll
                for (int mt = 0; mt < 4; ++mt)
                    acc[nt][mt] = MFMA16(a4[mt], bfr, acc[nt][mt]);
            }
        }
        __syncthreads();   // b2: hs reads done; qk stores may clobber
        // q (cols 0..31), k (cols 32..63) -> swizzled wave-private LDS (transpose)
        #pragma unroll
        for (int nt = 0; nt < 4; ++nt) {
            #pragma unroll
            for (int mt = 0; mt < 4; ++mt)
                #pragma unroll
                for (int rg = 0; rg < 4; ++rg) {
                    const int row = mt*16 + l4*4 + rg;
                    const int byteoff = (row*128 + (nt*16 + l15)*2) ^ ((row & 7) << 4);
                    *reinterpret_cast<short*>(qkb + byteoff) = f2bf(acc[nt][mt][rg]);
                }
        }
        // v -> registers, permuted-k PV A-fragments
        #pragma unroll
        for (int md = 0; md < 2; ++md)
            #pragma unroll
            for (int kst = 0; kst < 2; ++kst)
                vfrag[md][kst] = (u32x4){
                    pktrunc(acc[4+md][2*kst  ][0], acc[4+md][2*kst  ][1]),
                    pktrunc(acc[4+md][2*kst  ][2], acc[4+md][2*kst  ][3]),
                    pktrunc(acc[4+md][2*kst+1][0], acc[4+md][2*kst+1][1]),
                    pktrunc(acc[4+md][2*kst+1][2], acc[4+md][2*kst+1][3])};
    }
    // no barrier: qk store->read is same-wave (in-wave LDS ordering, R6/R9 precedent)

    // ---- S^T = K @ Q^T (wave = head, swizzled wave-private LDS reads) ----
    f32x4 st[4][4];    // [mtKey][ntQuery]
    {
        bf16x8 kf[4], qf[4];
        #pragma unroll
        for (int mt = 0; mt < 4; ++mt) {
            const int row = mt*16 + l15;
            kf[mt] = *reinterpret_cast<const bf16x8*>(
                qkb + ((row*128 + 64 + l4*16) ^ ((row & 7) << 4)));
        }
        #pragma unroll
        for (int nt = 0; nt < 4; ++nt) {
            const int row = nt*16 + l15;
            qf[nt] = *reinterpret_cast<const bf16x8*>(
                qkb + ((row*128 + l4*16) ^ ((row & 7) << 4)));
        }
        #pragma unroll
        for (int mt = 0; mt < 4; ++mt)
            #pragma unroll
            for (int nt = 0; nt < 4; ++nt)
                st[mt][nt] = MFMA16(kf[mt], qf[nt], ((f32x4){0.f,0.f,0.f,0.f}));
    }
    __syncthreads();   // b3: qk frag loads done; os stores may clobber

    // ---- softmax over keys (in-lane 13 live + 2 shfl), pack P^T ----
    unsigned pk[4][4][2];   // [ntQuery][mtKey][pair]
    #pragma unroll
    for (int nq = 0; nq < 4; ++nq) {
        const int qc = (nq*16 + l15) < WT ? (nq*16 + l15) : 48;
        const float* bp = biasp + (wv*49 + qc)*64;
        float v[13];
        #pragma unroll
        for (int mk = 0; mk < 3; ++mk) {
            const float4 b4 = *reinterpret_cast<const float4*>(&bp[mk*16 + l4*4]);
            v[mk*4+0] = fmaf(st[mk][nq][0], SCALE, b4.x);
            v[mk*4+1] = fmaf(st[mk][nq][1], SCALE, b4.y);
            v[mk*4+2] = fmaf(st[mk][nq][2], SCALE, b4.z);
            v[mk*4+3] = fmaf(st[mk][nq][3], SCALE, b4.w);
        }
        v[12] = (l4 == 0) ? fmaf(st[3][nq][0], SCALE, bp[48]) : -1e30f;  // key 48
        float mx = v[0];
        #pragma unroll
        for (int t = 1; t < 13; ++t) mx = fmaxf(mx, v[t]);
        mx = fmaxf(mx, __shfl_xor(mx, 16));
        mx = fmaxf(mx, __shfl_xor(mx, 32));
        float sum = 0.f;
        #pragma unroll
        for (int t = 0; t < 13; ++t) { v[t] = __expf(v[t] - mx); sum += v[t]; }
        sum += __shfl_xor(sum, 16);
        sum += __shfl_xor(sum, 32);
        const float inv = 1.f / sum;
        #pragma unroll
        for (int mk = 0; mk < 3; ++mk) {
            pk[nq][mk][0] = pktrunc(v[mk*4+0]*inv, v[mk*4+1]*inv);
            pk[nq][mk][1] = pktrunc(v[mk*4+2]*inv, v[mk*4+3]*inv);
        }
        pk[nq][3][0] = pktrunc(v[12]*inv, 0.f);
        pk[nq][3][1] = 0u;
    }

    // ---- PV: o^T = V^T @ P^T — BOTH operands from registers ----
    {
        f32x4 oc[2][4];   // [mtDim][ntQuery]
        #pragma unroll
        for (int md = 0; md < 2; ++md)
            #pragma unroll
            for (int nq = 0; nq < 4; ++nq)
                oc[md][nq] = (f32x4){0.f,0.f,0.f,0.f};
        #pragma unroll
        for (int kst = 0; kst < 2; ++kst) {
            #pragma unroll
            for (int nq = 0; nq < 4; ++nq) {
                const bf16x8 bp8 = __builtin_bit_cast(bf16x8,
                    (u32x4){pk[nq][2*kst][0], pk[nq][2*kst][1], pk[nq][2*kst+1][0], pk[nq][2*kst+1][1]});
                #pragma unroll
                for (int md = 0; md < 2; ++md)
                    oc[md][nq] = MFMA16(__builtin_bit_cast(bf16x8, vfrag[md][kst]), bp8, oc[md][nq]);
            }
        }
        // os store (transpose back): os[query][inner]
        #pragma unroll
        for (int md = 0; md < 2; ++md)
            #pragma unroll
            for (int nq = 0; nq < 4; ++nq) {
                const unsigned lo = pktrunc(oc[md][nq][0], oc[md][nq][1]);
                const unsigned hi = pktrunc(oc[md][nq][2], oc[md][nq][3]);
                *reinterpret_cast<unsigned long long*>(
                    &os[(nq*16 + l15)*OSS + wv*32 + md*16 + l4*4]) =
                    ((unsigned long long)hi << 32) | lo;
            }
    }

    // prefetch proj weights + biases + LN2 params (global, LDS-independent)
    bf16x8 wofr[4][6];
    float bo6[6], g6[6], be6[6], b26[6];
    #pragma unroll
    for (int nt = 0; nt < 6; ++nt) {
        bo6[nt] = b_out[nt*16 + l15];
        g6[nt]  = ln2_g[nt*16 + l15];
        be6[nt] = ln2_b[nt*16 + l15];
        b26[nt] = b2[nt*16 + l15];
        const short* wr = woutb + (size_t)(nt*16 + l15)*128 + l4*8;
        #pragma unroll
        for (int kst = 0; kst < 4; ++kst)
            wofr[kst][nt] = *reinterpret_cast<const bf16x8*>(wr + kst*32);
    }
    __syncthreads();   // b4: os ready

    // ---- proj: os[64x128] @ Wout^T + b_out + x -> yreg ----
    float yreg[6][4];
    {
        bf16x8 afr[4];
        #pragma unroll
        for (int kst = 0; kst < 4; ++kst)
            afr[kst] = *reinterpret_cast<const bf16x8*>(&os[(wv*16 + l15)*OSS + kst*32 + l4*8]);
        __syncthreads();   // b5: os frag loads done; h2 stores may clobber
        #pragma unroll
        for (int nt = 0; nt < 6; ++nt) {
            f32x4 acc = (f32x4){0.f,0.f,0.f,0.f};
            #pragma unroll
            for (int kst = 0; kst < 4; ++kst)
                acc = MFMA16(afr[kst], wofr[kst][nt], acc);
            #pragma unroll
            for (int rg = 0; rg < 4; ++rg) {
                const int tok = wv*16 + l4*4 + rg;
                float r = acc[rg] + bo6[nt];
                if (tok < WT) {
                    const size_t gi = ((size_t)b * NTOK + (size_t)(xr*7 + tok/7) * IMG + (yr*7 + tok%7)) * DIM + nt*16 + l15;
                    r += x[gi];
                }
                yreg[nt][rg] = r;
            }
        }
    }

    // ---- LN2 in-register (row over 16 l15-lanes x 6 nt) ----
    float mu4[4], rs4[4];
    #pragma unroll
    for (int rg = 0; rg < 4; ++rg) {
        float s = 0.f, s2 = 0.f;
        #pragma unroll
        for (int nt = 0; nt < 6; ++nt) { const float v = yreg[nt][rg]; s += v; s2 += v*v; }
        s  += __shfl_xor(s, 1);  s  += __shfl_xor(s, 2);  s  += __shfl_xor(s, 4);  s  += __shfl_xor(s, 8);
        s2 += __shfl_xor(s2, 1); s2 += __shfl_xor(s2, 2); s2 += __shfl_xor(s2, 4); s2 += __shfl_xor(s2, 8);
        const float m = s * (1.f/96.f);
        mu4[rg] = m;
        rs4[rg] = rsqrtf(s2 * (1.f/96.f) - m*m + 1e-5f);
    }
    #pragma unroll
    for (int nt = 0; nt < 6; ++nt)
        #pragma unroll
        for (int rg = 0; rg < 4; ++rg)
            h2[(wv*16 + l4*4 + rg)*104 + nt*16 + l15] =
                f2bf((yreg[nt][rg] - mu4[rg]) * rs4[rg] * g6[nt] + be6[nt]);
    __syncthreads();   // b6: h2 ready

    // ---- FFN: three 128-col chunks; GEMM1(GELU->ts) then GEMM2 k-partials ----
    f32x4 acc2[6];
    #pragma unroll
    for (int nt = 0; nt < 6; ++nt) acc2[nt] = (f32x4){0.f,0.f,0.f,0.f};
    bf16x8 af[3][4];
    #pragma unroll
    for (int k3 = 0; k3 < 3; ++k3)
        #pragma unroll
        for (int mt = 0; mt < 4; ++mt)
            af[k3][mt] = *reinterpret_cast<const bf16x8*>(&h2[(mt*16 + l15)*104 + k3*32 + l4*8]);

    #pragma unroll
    for (int ch = 0; ch < 3; ++ch) {
        // GEMM1: wave owns 2 column tiles of this 128-col chunk
        #pragma unroll
        for (int n2 = 0; n2 < 2; ++n2) {
            const int c0 = ch*128 + wv*32 + n2*16;
            const short* wr = w1b + (size_t)(c0 + l15)*96 + l4*8;
            f32x4 a1[4];
            #pragma unroll
            for (int mt = 0; mt < 4; ++mt) a1[mt] = (f32x4){0.f,0.f,0.f,0.f};
            #pragma unroll
            for (int k3 = 0; k3 < 3; ++k3) {
                const bf16x8 bf = *reinterpret_cast<const bf16x8*>(wr + k3*32);
                #pragma unroll
                for (int mt = 0; mt < 4; ++mt)
                    a1[mt] = MFMA16(af[k3][mt], bf, a1[mt]);
            }
            const float bb = b1[c0 + l15];
            #pragma unroll
            for (int mt = 0; mt < 4; ++mt)
                #pragma unroll
                for (int rg = 0; rg < 4; ++rg)
                    ts[(mt*16 + l4*4 + rg)*TSS + wv*32 + n2*16 + l15] = f2bf(gelu_f(a1[mt][rg] + bb));
        }
        __syncthreads();   // ts chunk ready
        // GEMM2 partial over this chunk's 128 k-values
        #pragma unroll
        for (int kl = 0; kl < 4; ++kl) {
            const bf16x8 at = *reinterpret_cast<const bf16x8*>(&ts[(wv*16 + l15)*TSS + kl*32 + l4*8]);
            #pragma unroll
            for (int nt = 0; nt < 6; ++nt) {
                const bf16x8 wf = *reinterpret_cast<const bf16x8*>(
                    w2b + (size_t)(nt*16 + l15)*384 + ch*128 + kl*32 + l4*8);
                acc2[nt] = MFMA16(at, wf, acc2[nt]);
            }
        }
        if (ch < 2) __syncthreads();   // ts reads done before next chunk overwrites
    }

    // ---- final: y = gemm2 + b2 + yreg, single global write ----
    #pragma unroll
    for (int nt = 0; nt < 6; ++nt)
        #pragma unroll
        for (int rg = 0; rg < 4; ++rg) {
            const int tok = wv*16 + l4*4 + rg;
            if (tok < WT) {
                const size_t gi = ((size_t)b * NTOK + (size_t)(xr*7 + tok/7) * IMG + (yr*7 + tok%7)) * DIM + nt*16 + l15;
                y[gi] = acc2[nt][rg] + b26[nt] + yreg[nt][rg];
            }
        }
}

extern "C" void kernel_launch(void* const* d_in, const int* in_sizes, int n_in,
                              void* d_out, int out_size, void* d_ws, size_t ws_size,
                              hipStream_t stream) {
    const float* x     = (const float*)d_in[0];
    const float* w_qkv = (const float*)d_in[1];
    const float* w_out = (const float*)d_in[2];
    const float* b_out = (const float*)d_in[3];
    const float* rel_b = (const float*)d_in[4];
    const float* ln1_g = (const float*)d_in[5];
    const float* ln1_b = (const float*)d_in[6];
    const float* ln2_g = (const float*)d_in[7];
    const float* ln2_b = (const float*)d_in[8];
    const float* w1    = (const float*)d_in[9];
    const float* b1    = (const float*)d_in[10];
    const float* w2    = (const float*)d_in[11];
    const float* b2    = (const float*)d_in[12];
    float* y = (float*)d_out;
    char* ws = (char*)d_ws;

    prep_kernel<<<529, 256, 0, stream>>>(w_qkv, w_out, w1, w2, rel_b, ws);
    fused_kernel<<<NB * 32 * 32, 256, 0, stream>>>(x, ws, b_out, ln1_g, ln1_b,
                                                   ln2_g, ln2_b, b1, b2, y);
}

// Round 11
// 499.008 us; speedup vs baseline: 1.3045x; 1.3045x over previous
//
#include <hip/hip_runtime.h>
#include <math.h>

#define NB    8
#define IMG   224
#define NTOK  (IMG*IMG)          // 50176 per batch
#define DIM   96
#define INR   128
#define HIDN  384
#define WT    49
#define SCALE 0.17677669529663687f
#define QKS   72                 // qk LDS row stride (shorts): q cols 0..31, k cols 32..63
#define OSS   136                // os row stride (shorts)
#define TSS   200                // ts row stride (shorts)

typedef __attribute__((ext_vector_type(8))) short bf16x8;
typedef __attribute__((ext_vector_type(4))) float f32x4;
typedef __attribute__((ext_vector_type(4))) unsigned int u32x4;

#define MFMA16(a,b,c) __builtin_amdgcn_mfma_f32_16x16x32_bf16((a),(b),(c),0,0,0)

__device__ __forceinline__ short f2bf(float f) {
    unsigned u = __builtin_bit_cast(unsigned, f);
    u += 0x7fffu + ((u >> 16) & 1u);
    return (short)(u >> 16);
}

// truncating pack of two f32 -> packed bf16x2 (lo in low 16)
__device__ __forceinline__ unsigned pktrunc(float lo, float hi) {
    return (__builtin_bit_cast(unsigned, hi) & 0xFFFF0000u) |
           (__builtin_bit_cast(unsigned, lo) >> 16);
}

// tanh-form GELU
__device__ __forceinline__ float gelu_f(float z) {
    const float u = z * 1.5957691216057308f * fmaf(0.044715f * z, z, 1.f);
    return z / (1.f + __expf(-u));
}

// fragment-major weight load: wave reads contiguous 1KB (tile*1024B + lane*16B)
__device__ __forceinline__ bf16x8 ldfrag(const short* base, int tile, int lane) {
    return *reinterpret_cast<const bf16x8*>(base + ((tile << 6) + lane) * 8);
}

// ---------- prep: weights -> bf16 in FRAGMENT-MAJOR layout; rel bias gathered ----------
// For a [N][K] matrix, tile (r,c) covers rows r*16..+15, k-cols c*32..+31.
// dst[(tile*64 + lane)*8 + j] = src[(r*16 + (lane&15))*K + c*32 + (lane>>4)*8 + j]
// -> in-kernel MFMA B-frag loads become perfectly coalesced (1KB/wave-instr).
__global__ void prep_kernel(const float* __restrict__ wqkv, const float* __restrict__ wout,
                            const float* __restrict__ w1,   const float* __restrict__ w2,
                            const float* __restrict__ rel_bias, char* __restrict__ ws)
{
    short* wqkvb = (short*)ws;                 // 36864 elems, tiles r<24, c<3
    short* woutb = (short*)(ws + 73728);       // 12288, tiles r<6, c<4
    short* w1b   = (short*)(ws + 98304);       // 36864, tiles r<24, c<3
    short* w2b   = (short*)(ws + 172032);      // 36864, tiles r<6, c<12
    float* biasp = (float*)(ws + 245760);      // [4][49][64] fp32, pre-scaled, key-padded
    const int idx = blockIdx.x * 256 + threadIdx.x;
    if (idx < 36864) {
        const int tile = idx >> 9, lane = (idx >> 3) & 63, j = idx & 7;
        const int r = tile / 3, c = tile % 3;
        wqkvb[idx] = f2bf(wqkv[(r*16 + (lane & 15))*96 + c*32 + (lane >> 4)*8 + j]);
    } else if (idx < 49152) {
        const int t = idx - 36864;
        const int tile = t >> 9, lane = (t >> 3) & 63, j = t & 7;
        const int r = tile >> 2, c = tile & 3;
        woutb[t] = f2bf(wout[(r*16 + (lane & 15))*128 + c*32 + (lane >> 4)*8 + j]);
    } else if (idx < 86016) {
        const int t = idx - 49152;
        const int tile = t >> 9, lane = (t >> 3) & 63, j = t & 7;
        const int r = tile / 3, c = tile % 3;
        w1b[t] = f2bf(w1[(r*16 + (lane & 15))*96 + c*32 + (lane >> 4)*8 + j]);
    } else if (idx < 122880) {
        const int t = idx - 86016;
        const int tile = t >> 9, lane = (t >> 3) & 63, j = t & 7;
        const int r = tile / 12, c = tile % 12;
        w2b[t] = f2bf(w2[(r*16 + (lane & 15))*384 + c*32 + (lane >> 4)*8 + j]);
    } else if (idx < 135424) {
        const int t = idx - 122880;
        const int h = t / 3136, r = t % 3136, q = r / 64, k = r % 64;
        float v = 0.f;
        if (k < 49) {
            const int rel = (q/7 - k/7 + 6) * 13 + (q%7 - k%7 + 6);
            v = rel_bias[rel * 4 + h] * SCALE;
        }
        biasp[t] = v;
    }
}

// ---------- fused kernel: LN1+qkv+attn+proj+LN2+FFN, one block = one 7x7 window ----------
// Structure identical to R9 (best variant); only weight addressing changed to fragment-major.
// LDS pool (38912 B), staged aliasing:
//   stage A: hs[64][104]            [0,13312)
//   stage B: qk[4][64][QKS]         [0,36864)   wave-private q|k   (aliases hs; barrier b2)
//   stage C: os[64][OSS]            [0,17408)   (aliases qk;  barrier b3)
//   stage D: h2[64][104]            [0,13312)   (aliases os;  barrier b5)
//            ts[64][TSS]            [13312,38912)
__global__ __launch_bounds__(256, 3) void fused_kernel(
    const float* __restrict__ x, const char* __restrict__ ws,
    const float* __restrict__ b_out, const float* __restrict__ ln1_g,
    const float* __restrict__ ln1_b, const float* __restrict__ ln2_g,
    const float* __restrict__ ln2_b, const float* __restrict__ b1,
    const float* __restrict__ b2, float* __restrict__ y)
{
    __shared__ __align__(16) char pool[38912];
    short* hs = (short*)pool;
    short* qk = (short*)pool;
    short* os = (short*)pool;
    short* h2 = (short*)pool;
    short* ts = (short*)(pool + 13312);

    const short* wqkvb = (const short*)ws;
    const short* woutb = (const short*)(ws + 73728);
    const short* w1b   = (const short*)(ws + 98304);
    const short* w2b   = (const short*)(ws + 172032);
    const float* biasp = (const float*)(ws + 245760);

    const int tid = threadIdx.x;
    const int wv  = tid >> 6;         // wave = head (attn) / M-tile (proj,FFN)
    const int lane = tid & 63;
    const int l15 = tid & 15;
    const int l4  = (tid & 63) >> 4;
    const int wid = blockIdx.x;
    const int b = wid >> 10, xr = (wid >> 5) & 31, yr = wid & 31;
    const int qkbase = wv * 64 * QKS;

    // ---- LN1: 4 threads per row ----
    if (tid < 196) {
        const int i = tid >> 2, g = tid & 3;
        const float* xp = x + ((size_t)b * NTOK + (size_t)(xr*7 + i/7) * IMG + (yr*7 + i%7)) * DIM + g*24;
        float v[24]; float s = 0.f, s2 = 0.f;
        #pragma unroll
        for (int c = 0; c < 6; ++c) {
            const float4 t4 = *reinterpret_cast<const float4*>(xp + c*4);
            v[c*4+0]=t4.x; v[c*4+1]=t4.y; v[c*4+2]=t4.z; v[c*4+3]=t4.w;
            s  += t4.x + t4.y + t4.z + t4.w;
            s2 += t4.x*t4.x + t4.y*t4.y + t4.z*t4.z + t4.w*t4.w;
        }
        s  += __shfl_xor(s, 1);  s  += __shfl_xor(s, 2);
        s2 += __shfl_xor(s2, 1); s2 += __shfl_xor(s2, 2);
        const float mu = s * (1.f/96.f);
        const float rs = rsqrtf(s2 * (1.f/96.f) - mu*mu + 1e-5f);
        #pragma unroll
        for (int c = 0; c < 24; ++c) {
            const int d = g*24 + c;
            hs[i*104 + d] = f2bf((v[c] - mu) * rs * ln1_g[d] + ln1_b[d]);
        }
    }
    for (int idx = tid; idx < 15*104; idx += 256) hs[49*104 + idx] = 0;
    __syncthreads();   // b1: hs ready

    // ---- qkv GEMM, head-partitioned: wave wv computes its own head's q,k,v ----
    u32x4 vfrag[2][2];   // V packed bf16, PV A-operand (regs only)
    {
        f32x4 acc[6][4];
        #pragma unroll
        for (int nt = 0; nt < 6; ++nt)
            #pragma unroll
            for (int mt = 0; mt < 4; ++mt)
                acc[nt][mt] = (f32x4){0.f,0.f,0.f,0.f};
        // k3-outer: A-frags 16 regs at a time
        #pragma unroll
        for (int k3 = 0; k3 < 3; ++k3) {
            bf16x8 a4[4];
            #pragma unroll
            for (int mt = 0; mt < 4; ++mt)
                a4[mt] = *reinterpret_cast<const bf16x8*>(&hs[(mt*16 + l15)*104 + k3*32 + l4*8]);
            #pragma unroll
            for (int nt = 0; nt < 6; ++nt) {
                const int r = (nt < 2 ? wv*2 + nt
                              : nt < 4 ? 8 + wv*2 + (nt-2)
                                       : 16 + wv*2 + (nt-4));
                const bf16x8 bfr = ldfrag(wqkvb, r*3 + k3, lane);
                #pragma unroll
                for (int mt = 0; mt < 4; ++mt)
                    acc[nt][mt] = MFMA16(a4[mt], bfr, acc[nt][mt]);
            }
        }
        __syncthreads();   // b2: hs reads done; qk stores may clobber
        // q (cols 0..31), k (cols 32..63) -> wave-private LDS (transpose)
        #pragma unroll
        for (int nt = 0; nt < 4; ++nt) {
            const int col0 = nt*16;
            #pragma unroll
            for (int mt = 0; mt < 4; ++mt)
                #pragma unroll
                for (int rg = 0; rg < 4; ++rg)
                    qk[qkbase + (mt*16 + l4*4 + rg)*QKS + col0 + l15] = f2bf(acc[nt][mt][rg]);
        }
        // v -> registers, permuted-k PV A-fragments
        #pragma unroll
        for (int md = 0; md < 2; ++md)
            #pragma unroll
            for (int kst = 0; kst < 2; ++kst)
                vfrag[md][kst] = (u32x4){
                    pktrunc(acc[4+md][2*kst  ][0], acc[4+md][2*kst  ][1]),
                    pktrunc(acc[4+md][2*kst  ][2], acc[4+md][2*kst  ][3]),
                    pktrunc(acc[4+md][2*kst+1][0], acc[4+md][2*kst+1][1]),
                    pktrunc(acc[4+md][2*kst+1][2], acc[4+md][2*kst+1][3])};
    }
    // no barrier: qk store->read is same-wave (in-wave LDS ordering, R6/R9 precedent)

    // ---- S^T = K @ Q^T (wave = head, wave-private LDS reads) ----
    f32x4 st[4][4];    // [mtKey][ntQuery]
    {
        bf16x8 kf[4], qf[4];
        #pragma unroll
        for (int mt = 0; mt < 4; ++mt)
            kf[mt] = *reinterpret_cast<const bf16x8*>(&qk[qkbase + (mt*16 + l15)*QKS + 32 + l4*8]);
        #pragma unroll
        for (int nt = 0; nt < 4; ++nt)
            qf[nt] = *reinterpret_cast<const bf16x8*>(&qk[qkbase + (nt*16 + l15)*QKS + l4*8]);
        #pragma unroll
        for (int mt = 0; mt < 4; ++mt)
            #pragma unroll
            for (int nt = 0; nt < 4; ++nt)
                st[mt][nt] = MFMA16(kf[mt], qf[nt], ((f32x4){0.f,0.f,0.f,0.f}));
    }
    __syncthreads();   // b3: qk frag loads done; os stores may clobber

    // ---- softmax over keys (in-lane 13 live + 2 shfl), pack P^T ----
    unsigned pk[4][4][2];   // [ntQuery][mtKey][pair]
    #pragma unroll
    for (int nq = 0; nq < 4; ++nq) {
        const int qc = (nq*16 + l15) < WT ? (nq*16 + l15) : 48;
        const float* bp = biasp + (wv*49 + qc)*64;
        float v[13];
        #pragma unroll
        for (int mk = 0; mk < 3; ++mk) {
            const float4 b4 = *reinterpret_cast<const float4*>(&bp[mk*16 + l4*4]);
            v[mk*4+0] = fmaf(st[mk][nq][0], SCALE, b4.x);
            v[mk*4+1] = fmaf(st[mk][nq][1], SCALE, b4.y);
            v[mk*4+2] = fmaf(st[mk][nq][2], SCALE, b4.z);
            v[mk*4+3] = fmaf(st[mk][nq][3], SCALE, b4.w);
        }
        v[12] = (l4 == 0) ? fmaf(st[3][nq][0], SCALE, bp[48]) : -1e30f;  // key 48
        float mx = v[0];
        #pragma unroll
        for (int t = 1; t < 13; ++t) mx = fmaxf(mx, v[t]);
        mx = fmaxf(mx, __shfl_xor(mx, 16));
        mx = fmaxf(mx, __shfl_xor(mx, 32));
        float sum = 0.f;
        #pragma unroll
        for (int t = 0; t < 13; ++t) { v[t] = __expf(v[t] - mx); sum += v[t]; }
        sum += __shfl_xor(sum, 16);
        sum += __shfl_xor(sum, 32);
        const float inv = 1.f / sum;
        #pragma unroll
        for (int mk = 0; mk < 3; ++mk) {
            pk[nq][mk][0] = pktrunc(v[mk*4+0]*inv, v[mk*4+1]*inv);
            pk[nq][mk][1] = pktrunc(v[mk*4+2]*inv, v[mk*4+3]*inv);
        }
        pk[nq][3][0] = pktrunc(v[12]*inv, 0.f);
        pk[nq][3][1] = 0u;
    }

    // ---- PV: o^T = V^T @ P^T — BOTH operands from registers ----
    {
        f32x4 oc[2][4];   // [mtDim][ntQuery]
        #pragma unroll
        for (int md = 0; md < 2; ++md)
            #pragma unroll
            for (int nq = 0; nq < 4; ++nq)
                oc[md][nq] = (f32x4){0.f,0.f,0.f,0.f};
        #pragma unroll
        for (int kst = 0; kst < 2; ++kst) {
            #pragma unroll
            for (int nq = 0; nq < 4; ++nq) {
                const bf16x8 bp8 = __builtin_bit_cast(bf16x8,
                    (u32x4){pk[nq][2*kst][0], pk[nq][2*kst][1], pk[nq][2*kst+1][0], pk[nq][2*kst+1][1]});
                #pragma unroll
                for (int md = 0; md < 2; ++md)
                    oc[md][nq] = MFMA16(__builtin_bit_cast(bf16x8, vfrag[md][kst]), bp8, oc[md][nq]);
            }
        }
        // os store (transpose back): os[query][inner]
        #pragma unroll
        for (int md = 0; md < 2; ++md)
            #pragma unroll
            for (int nq = 0; nq < 4; ++nq) {
                const unsigned lo = pktrunc(oc[md][nq][0], oc[md][nq][1]);
                const unsigned hi = pktrunc(oc[md][nq][2], oc[md][nq][3]);
                *reinterpret_cast<unsigned long long*>(
                    &os[(nq*16 + l15)*OSS + wv*32 + md*16 + l4*4]) =
                    ((unsigned long long)hi << 32) | lo;
            }
    }

    // prefetch proj weights + biases + LN2 params (global, LDS-independent, coalesced)
    bf16x8 wofr[4][6];
    float bo6[6], g6[6], be6[6], b26[6];
    #pragma unroll
    for (int nt = 0; nt < 6; ++nt) {
        bo6[nt] = b_out[nt*16 + l15];
        g6[nt]  = ln2_g[nt*16 + l15];
        be6[nt] = ln2_b[nt*16 + l15];
        b26[nt] = b2[nt*16 + l15];
        #pragma unroll
        for (int kst = 0; kst < 4; ++kst)
            wofr[kst][nt] = ldfrag(woutb, nt*4 + kst, lane);
    }
    __syncthreads();   // b4: os ready

    // ---- proj: os[64x128] @ Wout^T + b_out + x -> yreg ----
    float yreg[6][4];
    {
        bf16x8 afr[4];
        #pragma unroll
        for (int kst = 0; kst < 4; ++kst)
            afr[kst] = *reinterpret_cast<const bf16x8*>(&os[(wv*16 + l15)*OSS + kst*32 + l4*8]);
        __syncthreads();   // b5: os frag loads done; h2 stores may clobber
        #pragma unroll
        for (int nt = 0; nt < 6; ++nt) {
            f32x4 acc = (f32x4){0.f,0.f,0.f,0.f};
            #pragma unroll
            for (int kst = 0; kst < 4; ++kst)
                acc = MFMA16(afr[kst], wofr[kst][nt], acc);
            #pragma unroll
            for (int rg = 0; rg < 4; ++rg) {
                const int tok = wv*16 + l4*4 + rg;
                float r = acc[rg] + bo6[nt];
                if (tok < WT) {
                    const size_t gi = ((size_t)b * NTOK + (size_t)(xr*7 + tok/7) * IMG + (yr*7 + tok%7)) * DIM + nt*16 + l15;
                    r += x[gi];
                }
                yreg[nt][rg] = r;
            }
        }
    }

    // ---- LN2 in-register (row over 16 l15-lanes x 6 nt) ----
    float mu4[4], rs4[4];
    #pragma unroll
    for (int rg = 0; rg < 4; ++rg) {
        float s = 0.f, s2 = 0.f;
        #pragma unroll
        for (int nt = 0; nt < 6; ++nt) { const float v = yreg[nt][rg]; s += v; s2 += v*v; }
        s  += __shfl_xor(s, 1);  s  += __shfl_xor(s, 2);  s  += __shfl_xor(s, 4);  s  += __shfl_xor(s, 8);
        s2 += __shfl_xor(s2, 1); s2 += __shfl_xor(s2, 2); s2 += __shfl_xor(s2, 4); s2 += __shfl_xor(s2, 8);
        const float m = s * (1.f/96.f);
        mu4[rg] = m;
        rs4[rg] = rsqrtf(s2 * (1.f/96.f) - m*m + 1e-5f);
    }
    #pragma unroll
    for (int nt = 0; nt < 6; ++nt)
        #pragma unroll
        for (int rg = 0; rg < 4; ++rg)
            h2[(wv*16 + l4*4 + rg)*104 + nt*16 + l15] =
                f2bf((yreg[nt][rg] - mu4[rg]) * rs4[rg] * g6[nt] + be6[nt]);
    __syncthreads();   // b6: h2 ready

    // ---- FFN: GEMM1 halves (GELU -> ts) interleaved with GEMM2 k-partials ----
    f32x4 acc2[6];
    #pragma unroll
    for (int nt = 0; nt < 6; ++nt) acc2[nt] = (f32x4){0.f,0.f,0.f,0.f};

    #pragma unroll
    for (int al = 0; al < 2; ++al) {
        bf16x8 af[3][4];
        #pragma unroll
        for (int k3 = 0; k3 < 3; ++k3)
            #pragma unroll
            for (int mt = 0; mt < 4; ++mt)
                af[k3][mt] = *reinterpret_cast<const bf16x8*>(&h2[(mt*16 + l15)*104 + k3*32 + l4*8]);
        #pragma unroll
        for (int n3 = 0; n3 < 3; ++n3) {
            const int c0 = al*192 + wv*48 + n3*16;
            const int r1 = al*12 + wv*3 + n3;
            f32x4 a1[4];
            #pragma unroll
            for (int mt = 0; mt < 4; ++mt) a1[mt] = (f32x4){0.f,0.f,0.f,0.f};
            #pragma unroll
            for (int k3 = 0; k3 < 3; ++k3) {
                const bf16x8 bf = ldfrag(w1b, r1*3 + k3, lane);
                #pragma unroll
                for (int mt = 0; mt < 4; ++mt)
                    a1[mt] = MFMA16(af[k3][mt], bf, a1[mt]);
            }
            const float bb = b1[c0 + l15];
            #pragma unroll
            for (int mt = 0; mt < 4; ++mt)
                #pragma unroll
                for (int rg = 0; rg < 4; ++rg)
                    ts[(mt*16 + l4*4 + rg)*TSS + wv*48 + n3*16 + l15] = f2bf(gelu_f(a1[mt][rg] + bb));
        }
        __syncthreads();   // ts half ready
        bf16x8 at[6];
        #pragma unroll
        for (int kl = 0; kl < 6; ++kl)
            at[kl] = *reinterpret_cast<const bf16x8*>(&ts[(wv*16 + l15)*TSS + kl*32 + l4*8]);
        #pragma unroll
        for (int nt = 0; nt < 6; ++nt) {
            const int np = wv & 1;  // unused; keep mapping below explicit
            (void)np;
            #pragma unroll
            for (int kl = 0; kl < 6; ++kl)
                acc2[nt] = MFMA16(at[kl], ldfrag(w2b, nt*12 + al*6 + kl, lane), acc2[nt]);
        }
        if (al == 0) __syncthreads();   // ts reads done before half-1 overwrites
    }

    // ---- final: y = gemm2 + b2 + yreg, single global write ----
    #pragma unroll
    for (int nt = 0; nt < 6; ++nt)
        #pragma unroll
        for (int rg = 0; rg < 4; ++rg) {
            const int tok = wv*16 + l4*4 + rg;
            if (tok < WT) {
                const size_t gi = ((size_t)b * NTOK + (size_t)(xr*7 + tok/7) * IMG + (yr*7 + tok%7)) * DIM + nt*16 + l15;
                y[gi] = acc2[nt][rg] + b26[nt] + yreg[nt][rg];
            }
        }
}

extern "C" void kernel_launch(void* const* d_in, const int* in_sizes, int n_in,
                              void* d_out, int out_size, void* d_ws, size_t ws_size,
                              hipStream_t stream) {
    const float* x     = (const float*)d_in[0];
    const float* w_qkv = (const float*)d_in[1];
    const float* w_out = (const float*)d_in[2];
    const float* b_out = (const float*)d_in[3];
    const float* rel_b = (const float*)d_in[4];
    const float* ln1_g = (const float*)d_in[5];
    const float* ln1_b = (const float*)d_in[6];
    const float* ln2_g = (const float*)d_in[7];
    const float* ln2_b = (const float*)d_in[8];
    const float* w1    = (const float*)d_in[9];
    const float* b1    = (const float*)d_in[10];
    const float* w2    = (const float*)d_in[11];
    const float* b2    = (const float*)d_in[12];
    float* y = (float*)d_out;
    char* ws = (char*)d_ws;

    prep_kernel<<<529, 256, 0, stream>>>(w_qkv, w_out, w1, w2, rel_b, ws);
    fused_kernel<<<NB * 32 * 32, 256, 0, stream>>>(x, ws, b_out, ln1_g, ln1_b,
                                                   ln2_g, ln2_b, b1, b2, y);
}

// Round 12
// 496.467 us; speedup vs baseline: 1.3112x; 1.0051x over previous
//
#include <hip/hip_runtime.h>
#include <math.h>

#define NB    8
#define IMG   224
#define NTOK  (IMG*IMG)          // 50176 per batch
#define DIM   96
#define INR   128
#define HIDN  384
#define WT    49
#define SCALE 0.17677669529663687f
#define QKS   72                 // qk LDS row stride (shorts): q cols 0..31, k cols 32..63
#define OSS   136                // os row stride (shorts)
#define TSS   200                // ts row stride (shorts)

typedef __attribute__((ext_vector_type(8))) short bf16x8;
typedef __attribute__((ext_vector_type(4))) float f32x4;
typedef __attribute__((ext_vector_type(4))) unsigned int u32x4;

#define MFMA16(a,b,c) __builtin_amdgcn_mfma_f32_16x16x32_bf16((a),(b),(c),0,0,0)

__device__ __forceinline__ short f2bf(float f) {
    unsigned u = __builtin_bit_cast(unsigned, f);
    u += 0x7fffu + ((u >> 16) & 1u);
    return (short)(u >> 16);
}

// truncating pack of two f32 -> packed bf16x2 (lo in low 16)
__device__ __forceinline__ unsigned pktrunc(float lo, float hi) {
    return (__builtin_bit_cast(unsigned, hi) & 0xFFFF0000u) |
           (__builtin_bit_cast(unsigned, lo) >> 16);
}

// tanh-form GELU
__device__ __forceinline__ float gelu_f(float z) {
    const float u = z * 1.5957691216057308f * fmaf(0.044715f * z, z, 1.f);
    return z / (1.f + __expf(-u));
}

// fragment-major weight load: wave reads contiguous 1KB (tile*1024B + lane*16B)
__device__ __forceinline__ bf16x8 ldfrag(const short* base, int tile, int lane) {
    return *reinterpret_cast<const bf16x8*>(base + ((tile << 6) + lane) * 8);
}

// ---------- prep: weights -> bf16 in FRAGMENT-MAJOR layout; rel bias gathered ----------
__global__ void prep_kernel(const float* __restrict__ wqkv, const float* __restrict__ wout,
                            const float* __restrict__ w1,   const float* __restrict__ w2,
                            const float* __restrict__ rel_bias, char* __restrict__ ws)
{
    short* wqkvb = (short*)ws;                 // 36864 elems, tiles r<24, c<3
    short* woutb = (short*)(ws + 73728);       // 12288, tiles r<6, c<4
    short* w1b   = (short*)(ws + 98304);       // 36864, tiles r<24, c<3
    short* w2b   = (short*)(ws + 172032);      // 36864, tiles r<6, c<12
    float* biasp = (float*)(ws + 245760);      // [4][49][64] fp32, pre-scaled, key-padded
    const int idx = blockIdx.x * 256 + threadIdx.x;
    if (idx < 36864) {
        const int tile = idx >> 9, lane = (idx >> 3) & 63, j = idx & 7;
        const int r = tile / 3, c = tile % 3;
        wqkvb[idx] = f2bf(wqkv[(r*16 + (lane & 15))*96 + c*32 + (lane >> 4)*8 + j]);
    } else if (idx < 49152) {
        const int t = idx - 36864;
        const int tile = t >> 9, lane = (t >> 3) & 63, j = t & 7;
        const int r = tile >> 2, c = tile & 3;
        woutb[t] = f2bf(wout[(r*16 + (lane & 15))*128 + c*32 + (lane >> 4)*8 + j]);
    } else if (idx < 86016) {
        const int t = idx - 49152;
        const int tile = t >> 9, lane = (t >> 3) & 63, j = t & 7;
        const int r = tile / 3, c = tile % 3;
        w1b[t] = f2bf(w1[(r*16 + (lane & 15))*96 + c*32 + (lane >> 4)*8 + j]);
    } else if (idx < 122880) {
        const int t = idx - 86016;
        const int tile = t >> 9, lane = (t >> 3) & 63, j = t & 7;
        const int r = tile / 12, c = tile % 12;
        w2b[t] = f2bf(w2[(r*16 + (lane & 15))*384 + c*32 + (lane >> 4)*8 + j]);
    } else if (idx < 135424) {
        const int t = idx - 122880;
        const int h = t / 3136, r = t % 3136, q = r / 64, k = r % 64;
        float v = 0.f;
        if (k < 49) {
            const int rel = (q/7 - k/7 + 6) * 13 + (q%7 - k%7 + 6);
            v = rel_bias[rel * 4 + h] * SCALE;
        }
        biasp[t] = v;
    }
}

// ---------- fused kernel: LN1+qkv+attn+proj+LN2+FFN, one block = one 7x7 window ----------
// LDS pool (38912 B), staged aliasing (R12: os moved OFF h2's region -> barrier b5 deleted):
//   stage A: hs[64][104]            [0,13312)
//   stage B: qk[4][64][QKS]         [0,36864)       wave-private q|k (aliases hs; barrier b2)
//   stage C: os[64][OSS]            [13312,30720)   (aliases qk heads>=1; barrier b3)
//   stage D: h2[64][104]            [0,13312)       (disjoint from os -> no b5)
//            ts[64][TSS]            [13312,38912)   (overlaps os; os dead before b6)
__global__ __launch_bounds__(256, 3) void fused_kernel(
    const float* __restrict__ x, const char* __restrict__ ws,
    const float* __restrict__ b_out, const float* __restrict__ ln1_g,
    const float* __restrict__ ln1_b, const float* __restrict__ ln2_g,
    const float* __restrict__ ln2_b, const float* __restrict__ b1,
    const float* __restrict__ b2, float* __restrict__ y)
{
    __shared__ __align__(16) char pool[38912];
    short* hs = (short*)pool;
    short* qk = (short*)pool;
    short* os = (short*)(pool + 13312);
    short* h2 = (short*)pool;
    short* ts = (short*)(pool + 13312);

    const short* wqkvb = (const short*)ws;
    const short* woutb = (const short*)(ws + 73728);
    const short* w1b   = (const short*)(ws + 98304);
    const short* w2b   = (const short*)(ws + 172032);
    const float* biasp = (const float*)(ws + 245760);

    const int tid = threadIdx.x;
    const int wv  = tid >> 6;         // wave = head (attn) / M-tile (proj,FFN)
    const int lane = tid & 63;
    const int l15 = tid & 15;
    const int l4  = (tid & 63) >> 4;
    const int wid = blockIdx.x;
    const int b = wid >> 10, xr = (wid >> 5) & 31, yr = wid & 31;
    const int qkbase = wv * 64 * QKS;

    // ---- LN1: 4 threads per row ----
    if (tid < 196) {
        const int i = tid >> 2, g = tid & 3;
        const float* xp = x + ((size_t)b * NTOK + (size_t)(xr*7 + i/7) * IMG + (yr*7 + i%7)) * DIM + g*24;
        float v[24]; float s = 0.f, s2 = 0.f;
        #pragma unroll
        for (int c = 0; c < 6; ++c) {
            const float4 t4 = *reinterpret_cast<const float4*>(xp + c*4);
            v[c*4+0]=t4.x; v[c*4+1]=t4.y; v[c*4+2]=t4.z; v[c*4+3]=t4.w;
            s  += t4.x + t4.y + t4.z + t4.w;
            s2 += t4.x*t4.x + t4.y*t4.y + t4.z*t4.z + t4.w*t4.w;
        }
        s  += __shfl_xor(s, 1);  s  += __shfl_xor(s, 2);
        s2 += __shfl_xor(s2, 1); s2 += __shfl_xor(s2, 2);
        const float mu = s * (1.f/96.f);
        const float rs = rsqrtf(s2 * (1.f/96.f) - mu*mu + 1e-5f);
        #pragma unroll
        for (int c = 0; c < 24; ++c) {
            const int d = g*24 + c;
            hs[i*104 + d] = f2bf((v[c] - mu) * rs * ln1_g[d] + ln1_b[d]);
        }
    }
    for (int idx = tid; idx < 15*104; idx += 256) hs[49*104 + idx] = 0;
    __syncthreads();   // b1: hs ready

    // ---- qkv GEMM, head-partitioned: wave wv computes its own head's q,k,v ----
    u32x4 vfrag[2][2];   // V packed bf16, PV A-operand (regs only)
    {
        f32x4 acc[6][4];
        #pragma unroll
        for (int nt = 0; nt < 6; ++nt)
            #pragma unroll
            for (int mt = 0; mt < 4; ++mt)
                acc[nt][mt] = (f32x4){0.f,0.f,0.f,0.f};
        // k3-outer: A-frags 16 regs at a time
        #pragma unroll
        for (int k3 = 0; k3 < 3; ++k3) {
            bf16x8 a4[4];
            #pragma unroll
            for (int mt = 0; mt < 4; ++mt)
                a4[mt] = *reinterpret_cast<const bf16x8*>(&hs[(mt*16 + l15)*104 + k3*32 + l4*8]);
            #pragma unroll
            for (int nt = 0; nt < 6; ++nt) {
                const int r = (nt < 2 ? wv*2 + nt
                              : nt < 4 ? 8 + wv*2 + (nt-2)
                                       : 16 + wv*2 + (nt-4));
                const bf16x8 bfr = ldfrag(wqkvb, r*3 + k3, lane);
                #pragma unroll
                for (int mt = 0; mt < 4; ++mt)
                    acc[nt][mt] = MFMA16(a4[mt], bfr, acc[nt][mt]);
            }
        }
        __syncthreads();   // b2: hs reads done; qk stores may clobber
        // q (cols 0..31), k (cols 32..63) -> wave-private LDS (transpose)
        #pragma unroll
        for (int nt = 0; nt < 4; ++nt) {
            const int col0 = nt*16;
            #pragma unroll
            for (int mt = 0; mt < 4; ++mt)
                #pragma unroll
                for (int rg = 0; rg < 4; ++rg)
                    qk[qkbase + (mt*16 + l4*4 + rg)*QKS + col0 + l15] = f2bf(acc[nt][mt][rg]);
        }
        // v -> registers, permuted-k PV A-fragments
        #pragma unroll
        for (int md = 0; md < 2; ++md)
            #pragma unroll
            for (int kst = 0; kst < 2; ++kst)
                vfrag[md][kst] = (u32x4){
                    pktrunc(acc[4+md][2*kst  ][0], acc[4+md][2*kst  ][1]),
                    pktrunc(acc[4+md][2*kst  ][2], acc[4+md][2*kst  ][3]),
                    pktrunc(acc[4+md][2*kst+1][0], acc[4+md][2*kst+1][1]),
                    pktrunc(acc[4+md][2*kst+1][2], acc[4+md][2*kst+1][3])};
    }
    // no barrier: qk store->read is same-wave (in-wave LDS ordering, R6/R9 precedent)

    // ---- S^T = K @ Q^T (wave = head, wave-private LDS reads) ----
    f32x4 st[4][4];    // [mtKey][ntQuery]
    {
        bf16x8 kf[4], qf[4];
        #pragma unroll
        for (int mt = 0; mt < 4; ++mt)
            kf[mt] = *reinterpret_cast<const bf16x8*>(&qk[qkbase + (mt*16 + l15)*QKS + 32 + l4*8]);
        #pragma unroll
        for (int nt = 0; nt < 4; ++nt)
            qf[nt] = *reinterpret_cast<const bf16x8*>(&qk[qkbase + (nt*16 + l15)*QKS + l4*8]);
        #pragma unroll
        for (int mt = 0; mt < 4; ++mt)
            #pragma unroll
            for (int nt = 0; nt < 4; ++nt)
                st[mt][nt] = MFMA16(kf[mt], qf[nt], ((f32x4){0.f,0.f,0.f,0.f}));
    }
    __syncthreads();   // b3: qk frag loads done; os stores may clobber

    // ---- softmax over keys (in-lane 13 live + 2 shfl), pack P^T ----
    unsigned pk[4][4][2];   // [ntQuery][mtKey][pair]
    #pragma unroll
    for (int nq = 0; nq < 4; ++nq) {
        const int qc = (nq*16 + l15) < WT ? (nq*16 + l15) : 48;
        const float* bp = biasp + (wv*49 + qc)*64;
        float v[13];
        #pragma unroll
        for (int mk = 0; mk < 3; ++mk) {
            const float4 b4 = *reinterpret_cast<const float4*>(&bp[mk*16 + l4*4]);
            v[mk*4+0] = fmaf(st[mk][nq][0], SCALE, b4.x);
            v[mk*4+1] = fmaf(st[mk][nq][1], SCALE, b4.y);
            v[mk*4+2] = fmaf(st[mk][nq][2], SCALE, b4.z);
            v[mk*4+3] = fmaf(st[mk][nq][3], SCALE, b4.w);
        }
        v[12] = (l4 == 0) ? fmaf(st[3][nq][0], SCALE, bp[48]) : -1e30f;  // key 48
        float mx = v[0];
        #pragma unroll
        for (int t = 1; t < 13; ++t) mx = fmaxf(mx, v[t]);
        mx = fmaxf(mx, __shfl_xor(mx, 16));
        mx = fmaxf(mx, __shfl_xor(mx, 32));
        float sum = 0.f;
        #pragma unroll
        for (int t = 0; t < 13; ++t) { v[t] = __expf(v[t] - mx); sum += v[t]; }
        sum += __shfl_xor(sum, 16);
        sum += __shfl_xor(sum, 32);
        const float inv = 1.f / sum;
        #pragma unroll
        for (int mk = 0; mk < 3; ++mk) {
            pk[nq][mk][0] = pktrunc(v[mk*4+0]*inv, v[mk*4+1]*inv);
            pk[nq][mk][1] = pktrunc(v[mk*4+2]*inv, v[mk*4+3]*inv);
        }
        pk[nq][3][0] = pktrunc(v[12]*inv, 0.f);
        pk[nq][3][1] = 0u;
    }

    // ---- prefetch x-residual (24 HBM loads) early: hidden under PV+stores+b4+proj issue ----
    float xres[6][4];
    #pragma unroll
    for (int nt = 0; nt < 6; ++nt)
        #pragma unroll
        for (int rg = 0; rg < 4; ++rg) {
            const int tok = wv*16 + l4*4 + rg;
            const int tokc = tok < WT ? tok : 48;   // clamp: pad rows read real data, discarded later
            xres[nt][rg] = x[((size_t)b * NTOK + (size_t)(xr*7 + tokc/7) * IMG + (yr*7 + tokc%7)) * DIM + nt*16 + l15];
        }

    // ---- PV: o^T = V^T @ P^T — BOTH operands from registers ----
    {
        f32x4 oc[2][4];   // [mtDim][ntQuery]
        #pragma unroll
        for (int md = 0; md < 2; ++md)
            #pragma unroll
            for (int nq = 0; nq < 4; ++nq)
                oc[md][nq] = (f32x4){0.f,0.f,0.f,0.f};
        #pragma unroll
        for (int kst = 0; kst < 2; ++kst) {
            #pragma unroll
            for (int nq = 0; nq < 4; ++nq) {
                const bf16x8 bp8 = __builtin_bit_cast(bf16x8,
                    (u32x4){pk[nq][2*kst][0], pk[nq][2*kst][1], pk[nq][2*kst+1][0], pk[nq][2*kst+1][1]});
                #pragma unroll
                for (int md = 0; md < 2; ++md)
                    oc[md][nq] = MFMA16(__builtin_bit_cast(bf16x8, vfrag[md][kst]), bp8, oc[md][nq]);
            }
        }
        // os store (transpose back): os[query][inner]
        #pragma unroll
        for (int md = 0; md < 2; ++md)
            #pragma unroll
            for (int nq = 0; nq < 4; ++nq) {
                const unsigned lo = pktrunc(oc[md][nq][0], oc[md][nq][1]);
                const unsigned hi = pktrunc(oc[md][nq][2], oc[md][nq][3]);
                *reinterpret_cast<unsigned long long*>(
                    &os[(nq*16 + l15)*OSS + wv*32 + md*16 + l4*4]) =
                    ((unsigned long long)hi << 32) | lo;
            }
    }

    // prefetch proj weights + biases + LN2 params + b1 (global, LDS-independent, coalesced)
    bf16x8 wofr[4][6];
    float bo6[6], g6[6], be6[6], b26[6], b1p[6];
    #pragma unroll
    for (int nt = 0; nt < 6; ++nt) {
        bo6[nt] = b_out[nt*16 + l15];
        g6[nt]  = ln2_g[nt*16 + l15];
        be6[nt] = ln2_b[nt*16 + l15];
        b26[nt] = b2[nt*16 + l15];
        #pragma unroll
        for (int kst = 0; kst < 4; ++kst)
            wofr[kst][nt] = ldfrag(woutb, nt*4 + kst, lane);
    }
    #pragma unroll
    for (int al = 0; al < 2; ++al)
        #pragma unroll
        for (int n3 = 0; n3 < 3; ++n3)
            b1p[al*3 + n3] = b1[al*192 + wv*48 + n3*16 + l15];
    __syncthreads();   // b4: os ready

    // ---- proj: os[64x128] @ Wout^T + b_out + xres -> yreg (no b5: h2 disjoint from os) ----
    float yreg[6][4];
    {
        bf16x8 afr[4];
        #pragma unroll
        for (int kst = 0; kst < 4; ++kst)
            afr[kst] = *reinterpret_cast<const bf16x8*>(&os[(wv*16 + l15)*OSS + kst*32 + l4*8]);
        #pragma unroll
        for (int nt = 0; nt < 6; ++nt) {
            f32x4 acc = (f32x4){0.f,0.f,0.f,0.f};
            #pragma unroll
            for (int kst = 0; kst < 4; ++kst)
                acc = MFMA16(afr[kst], wofr[kst][nt], acc);
            #pragma unroll
            for (int rg = 0; rg < 4; ++rg)
                yreg[nt][rg] = acc[rg] + bo6[nt] + xres[nt][rg];
        }
    }

    // ---- LN2 in-register (row over 16 l15-lanes x 6 nt) ----
    float mu4[4], rs4[4];
    #pragma unroll
    for (int rg = 0; rg < 4; ++rg) {
        float s = 0.f, s2 = 0.f;
        #pragma unroll
        for (int nt = 0; nt < 6; ++nt) { const float v = yreg[nt][rg]; s += v; s2 += v*v; }
        s  += __shfl_xor(s, 1);  s  += __shfl_xor(s, 2);  s  += __shfl_xor(s, 4);  s  += __shfl_xor(s, 8);
        s2 += __shfl_xor(s2, 1); s2 += __shfl_xor(s2, 2); s2 += __shfl_xor(s2, 4); s2 += __shfl_xor(s2, 8);
        const float m = s * (1.f/96.f);
        mu4[rg] = m;
        rs4[rg] = rsqrtf(s2 * (1.f/96.f) - m*m + 1e-5f);
    }
    #pragma unroll
    for (int nt = 0; nt < 6; ++nt)
        #pragma unroll
        for (int rg = 0; rg < 4; ++rg)
            h2[(wv*16 + l4*4 + rg)*104 + nt*16 + l15] =
                f2bf((yreg[nt][rg] - mu4[rg]) * rs4[rg] * g6[nt] + be6[nt]);
    __syncthreads();   // b6: h2 ready (os fully consumed; ts may overwrite it after this)

    // ---- FFN: GEMM1 halves (GELU -> ts) interleaved with GEMM2 k-partials ----
    f32x4 acc2[6];
    #pragma unroll
    for (int nt = 0; nt < 6; ++nt) acc2[nt] = (f32x4){0.f,0.f,0.f,0.f};

    #pragma unroll
    for (int al = 0; al < 2; ++al) {
        bf16x8 af[3][4];
        #pragma unroll
        for (int k3 = 0; k3 < 3; ++k3)
            #pragma unroll
            for (int mt = 0; mt < 4; ++mt)
                af[k3][mt] = *reinterpret_cast<const bf16x8*>(&h2[(mt*16 + l15)*104 + k3*32 + l4*8]);
        #pragma unroll
        for (int n3 = 0; n3 < 3; ++n3) {
            const int r1 = al*12 + wv*3 + n3;
            f32x4 a1[4];
            #pragma unroll
            for (int mt = 0; mt < 4; ++mt) a1[mt] = (f32x4){0.f,0.f,0.f,0.f};
            #pragma unroll
            for (int k3 = 0; k3 < 3; ++k3) {
                const bf16x8 bf = ldfrag(w1b, r1*3 + k3, lane);
                #pragma unroll
                for (int mt = 0; mt < 4; ++mt)
                    a1[mt] = MFMA16(af[k3][mt], bf, a1[mt]);
            }
            const float bb = b1p[al*3 + n3];
            #pragma unroll
            for (int mt = 0; mt < 4; ++mt)
                #pragma unroll
                for (int rg = 0; rg < 4; ++rg)
                    ts[(mt*16 + l4*4 + rg)*TSS + wv*48 + n3*16 + l15] = f2bf(gelu_f(a1[mt][rg] + bb));
        }
        __syncthreads();   // ts half ready
        bf16x8 at[6];
        #pragma unroll
        for (int kl = 0; kl < 6; ++kl)
            at[kl] = *reinterpret_cast<const bf16x8*>(&ts[(wv*16 + l15)*TSS + kl*32 + l4*8]);
        #pragma unroll
        for (int nt = 0; nt < 6; ++nt) {
            #pragma unroll
            for (int kl = 0; kl < 6; ++kl)
                acc2[nt] = MFMA16(at[kl], ldfrag(w2b, nt*12 + al*6 + kl, lane), acc2[nt]);
        }
        if (al == 0) __syncthreads();   // ts reads done before half-1 overwrites
    }

    // ---- final: y = gemm2 + b2 + yreg, single global write ----
    #pragma unroll
    for (int nt = 0; nt < 6; ++nt)
        #pragma unroll
        for (int rg = 0; rg < 4; ++rg) {
            const int tok = wv*16 + l4*4 + rg;
            if (tok < WT) {
                const size_t gi = ((size_t)b * NTOK + (size_t)(xr*7 + tok/7) * IMG + (yr*7 + tok%7)) * DIM + nt*16 + l15;
                y[gi] = acc2[nt][rg] + b26[nt] + yreg[nt][rg];
            }
        }
}

extern "C" void kernel_launch(void* const* d_in, const int* in_sizes, int n_in,
                              void* d_out, int out_size, void* d_ws, size_t ws_size,
                              hipStream_t stream) {
    const float* x     = (const float*)d_in[0];
    const float* w_qkv = (const float*)d_in[1];
    const float* w_out = (const float*)d_in[2];
    const float* b_out = (const float*)d_in[3];
    const float* rel_b = (const float*)d_in[4];
    const float* ln1_g = (const float*)d_in[5];
    const float* ln1_b = (const float*)d_in[6];
    const float* ln2_g = (const float*)d_in[7];
    const float* ln2_b = (const float*)d_in[8];
    const float* w1    = (const float*)d_in[9];
    const float* b1    = (const float*)d_in[10];
    const float* w2    = (const float*)d_in[11];
    const float* b2    = (const float*)d_in[12];
    float* y = (float*)d_out;
    char* ws = (char*)d_ws;

    prep_kernel<<<529, 256, 0, stream>>>(w_qkv, w_out, w1, w2, rel_b, ws);
    fused_kernel<<<NB * 32 * 32, 256, 0, stream>>>(x, ws, b_out, ln1_g, ln1_b,
                                                   ln2_g, ln2_b, b1, b2, y);
}

// Round 13
// 454.086 us; speedup vs baseline: 1.4336x; 1.0933x over previous
//
#include <hip/hip_runtime.h>
#include <math.h>

#define NB    8
#define IMG   224
#define NTOK  (IMG*IMG)          // 50176 per batch
#define DIM   96
#define INR   128
#define HIDN  384
#define WT    49
#define SCALE 0.17677669529663687f
#define QKS   72                 // qk LDS row stride (shorts): q cols 0..31, k cols 32..63
#define OSS   136                // os row stride (shorts)
#define TSS   200                // ts row stride (shorts)

typedef __attribute__((ext_vector_type(8))) short bf16x8;
typedef __attribute__((ext_vector_type(4))) float f32x4;
typedef __attribute__((ext_vector_type(4))) unsigned int u32x4;

#define MFMA16(a,b,c) __builtin_amdgcn_mfma_f32_16x16x32_bf16((a),(b),(c),0,0,0)

__device__ __forceinline__ short f2bf(float f) {
    unsigned u = __builtin_bit_cast(unsigned, f);
    u += 0x7fffu + ((u >> 16) & 1u);
    return (short)(u >> 16);
}

// truncating pack of two f32 -> packed bf16x2 (lo in low 16)
__device__ __forceinline__ unsigned pktrunc(float lo, float hi) {
    return (__builtin_bit_cast(unsigned, hi) & 0xFFFF0000u) |
           (__builtin_bit_cast(unsigned, lo) >> 16);
}

// tanh-form GELU
__device__ __forceinline__ float gelu_f(float z) {
    const float u = z * 1.5957691216057308f * fmaf(0.044715f * z, z, 1.f);
    return z / (1.f + __expf(-u));
}

// fragment-major weight load: wave reads contiguous 1KB (tile*1024B + lane*16B)
__device__ __forceinline__ bf16x8 ldfrag(const short* base, int tile, int lane) {
    return *reinterpret_cast<const bf16x8*>(base + ((tile << 6) + lane) * 8);
}

// ---------- prep: weights -> bf16 in FRAGMENT-MAJOR layout; rel bias gathered ----------
__global__ void prep_kernel(const float* __restrict__ wqkv, const float* __restrict__ wout,
                            const float* __restrict__ w1,   const float* __restrict__ w2,
                            const float* __restrict__ rel_bias, char* __restrict__ ws)
{
    short* wqkvb = (short*)ws;                 // 36864 elems, tiles r<24, c<3
    short* woutb = (short*)(ws + 73728);       // 12288, tiles r<6, c<4
    short* w1b   = (short*)(ws + 98304);       // 36864, tiles r<24, c<3
    short* w2b   = (short*)(ws + 172032);      // 36864, tiles r<6, c<12
    float* biasp = (float*)(ws + 245760);      // [4][49][64] fp32, pre-scaled, key-padded
    const int idx = blockIdx.x * 256 + threadIdx.x;
    if (idx < 36864) {
        const int tile = idx >> 9, lane = (idx >> 3) & 63, j = idx & 7;
        const int r = tile / 3, c = tile % 3;
        wqkvb[idx] = f2bf(wqkv[(r*16 + (lane & 15))*96 + c*32 + (lane >> 4)*8 + j]);
    } else if (idx < 49152) {
        const int t = idx - 36864;
        const int tile = t >> 9, lane = (t >> 3) & 63, j = t & 7;
        const int r = tile >> 2, c = tile & 3;
        woutb[t] = f2bf(wout[(r*16 + (lane & 15))*128 + c*32 + (lane >> 4)*8 + j]);
    } else if (idx < 86016) {
        const int t = idx - 49152;
        const int tile = t >> 9, lane = (t >> 3) & 63, j = t & 7;
        const int r = tile / 3, c = tile % 3;
        w1b[t] = f2bf(w1[(r*16 + (lane & 15))*96 + c*32 + (lane >> 4)*8 + j]);
    } else if (idx < 122880) {
        const int t = idx - 86016;
        const int tile = t >> 9, lane = (t >> 3) & 63, j = t & 7;
        const int r = tile / 12, c = tile % 12;
        w2b[t] = f2bf(w2[(r*16 + (lane & 15))*384 + c*32 + (lane >> 4)*8 + j]);
    } else if (idx < 135424) {
        const int t = idx - 122880;
        const int h = t / 3136, r = t % 3136, q = r / 64, k = r % 64;
        float v = 0.f;
        if (k < 49) {
            const int rel = (q/7 - k/7 + 6) * 13 + (q%7 - k%7 + 6);
            v = rel_bias[rel * 4 + h] * SCALE;
        }
        biasp[t] = v;
    }
}

// ---------- fused kernel: LN1+qkv+attn+proj+LN2+FFN, one block = one 7x7 window ----------
// LDS pool (50176 B); hs and qk now DISJOINT (kills barrier b2, enables qkv reg-split):
//   stage A: hs[64][104]            [0,13312)
//   stage B: qk[4][64][QKS]         [13312,50176)   wave-private q|k (disjoint from hs!)
//   stage C: os[64][OSS]            [13312,30720)   (aliases qk; gated by b3)
//   stage D: h2[64][104]            [0,13312)       (aliases hs; hs dead pre-b3 -> no fence)
//            ts[64][TSS]            [13312,38912)   (aliases os; os dead pre-b6)
// 3 blocks/CU (150528 <= 163840). qkv split into passA(q,k: acc 64regs) + passB(v: 32regs)
// so the unified VGPR+AGPR live-set stays under the (256,3) budget -> no scratch spill.
__global__ __launch_bounds__(256, 3) void fused_kernel(
    const float* __restrict__ x, const char* __restrict__ ws,
    const float* __restrict__ b_out, const float* __restrict__ ln1_g,
    const float* __restrict__ ln1_b, const float* __restrict__ ln2_g,
    const float* __restrict__ ln2_b, const float* __restrict__ b1,
    const float* __restrict__ b2, float* __restrict__ y)
{
    __shared__ __align__(16) char pool[50176];
    short* hs = (short*)pool;
    short* qk = (short*)(pool + 13312);
    short* os = (short*)(pool + 13312);
    short* h2 = (short*)pool;
    short* ts = (short*)(pool + 13312);

    const short* wqkvb = (const short*)ws;
    const short* woutb = (const short*)(ws + 73728);
    const short* w1b   = (const short*)(ws + 98304);
    const short* w2b   = (const short*)(ws + 172032);
    const float* biasp = (const float*)(ws + 245760);

    const int tid = threadIdx.x;
    const int wv  = tid >> 6;         // wave = head (attn) / M-tile (proj,FFN)
    const int lane = tid & 63;
    const int l15 = tid & 15;
    const int l4  = (tid & 63) >> 4;
    const int wid = blockIdx.x;
    const int b = wid >> 10, xr = (wid >> 5) & 31, yr = wid & 31;
    const int qkbase = wv * 64 * QKS;

    // ---- LN1: 4 threads per row ----
    if (tid < 196) {
        const int i = tid >> 2, g = tid & 3;
        const float* xp = x + ((size_t)b * NTOK + (size_t)(xr*7 + i/7) * IMG + (yr*7 + i%7)) * DIM + g*24;
        float v[24]; float s = 0.f, s2 = 0.f;
        #pragma unroll
        for (int c = 0; c < 6; ++c) {
            const float4 t4 = *reinterpret_cast<const float4*>(xp + c*4);
            v[c*4+0]=t4.x; v[c*4+1]=t4.y; v[c*4+2]=t4.z; v[c*4+3]=t4.w;
            s  += t4.x + t4.y + t4.z + t4.w;
            s2 += t4.x*t4.x + t4.y*t4.y + t4.z*t4.z + t4.w*t4.w;
        }
        s  += __shfl_xor(s, 1);  s  += __shfl_xor(s, 2);
        s2 += __shfl_xor(s2, 1); s2 += __shfl_xor(s2, 2);
        const float mu = s * (1.f/96.f);
        const float rs = rsqrtf(s2 * (1.f/96.f) - mu*mu + 1e-5f);
        #pragma unroll
        for (int c = 0; c < 24; ++c) {
            const int d = g*24 + c;
            hs[i*104 + d] = f2bf((v[c] - mu) * rs * ln1_g[d] + ln1_b[d]);
        }
    }
    for (int idx = tid; idx < 15*104; idx += 256) hs[49*104 + idx] = 0;
    __syncthreads();   // b1: hs ready

    // ---- qkv pass A: q,k (acc[4][4] = 64 regs peak) ----
    {
        f32x4 acc[4][4];
        #pragma unroll
        for (int nt = 0; nt < 4; ++nt)
            #pragma unroll
            for (int mt = 0; mt < 4; ++mt)
                acc[nt][mt] = (f32x4){0.f,0.f,0.f,0.f};
        #pragma unroll
        for (int k3 = 0; k3 < 3; ++k3) {
            bf16x8 a4[4];
            #pragma unroll
            for (int mt = 0; mt < 4; ++mt)
                a4[mt] = *reinterpret_cast<const bf16x8*>(&hs[(mt*16 + l15)*104 + k3*32 + l4*8]);
            #pragma unroll
            for (int nt = 0; nt < 4; ++nt) {
                const int r = (nt < 2) ? wv*2 + nt : 8 + wv*2 + (nt-2);
                const bf16x8 bfr = ldfrag(wqkvb, r*3 + k3, lane);
                #pragma unroll
                for (int mt = 0; mt < 4; ++mt)
                    acc[nt][mt] = MFMA16(a4[mt], bfr, acc[nt][mt]);
            }
        }
        // q (cols 0..31), k (cols 32..63) -> wave-private LDS; qk disjoint from hs -> NO barrier
        #pragma unroll
        for (int nt = 0; nt < 4; ++nt) {
            const int col0 = nt*16;
            #pragma unroll
            for (int mt = 0; mt < 4; ++mt)
                #pragma unroll
                for (int rg = 0; rg < 4; ++rg)
                    qk[qkbase + (mt*16 + l4*4 + rg)*QKS + col0 + l15] = f2bf(acc[nt][mt][rg]);
        }
    }

    // ---- qkv pass B: v (acc[2][4] = 32 regs) -> vfrag registers ----
    u32x4 vfrag[2][2];   // V packed bf16, PV A-operand (regs only)
    {
        f32x4 accv[2][4];
        #pragma unroll
        for (int nv = 0; nv < 2; ++nv)
            #pragma unroll
            for (int mt = 0; mt < 4; ++mt)
                accv[nv][mt] = (f32x4){0.f,0.f,0.f,0.f};
        #pragma unroll
        for (int k3 = 0; k3 < 3; ++k3) {
            bf16x8 a4[4];
            #pragma unroll
            for (int mt = 0; mt < 4; ++mt)
                a4[mt] = *reinterpret_cast<const bf16x8*>(&hs[(mt*16 + l15)*104 + k3*32 + l4*8]);
            #pragma unroll
            for (int nv = 0; nv < 2; ++nv) {
                const bf16x8 bfr = ldfrag(wqkvb, (16 + wv*2 + nv)*3 + k3, lane);
                #pragma unroll
                for (int mt = 0; mt < 4; ++mt)
                    accv[nv][mt] = MFMA16(a4[mt], bfr, accv[nv][mt]);
            }
        }
        #pragma unroll
        for (int md = 0; md < 2; ++md)
            #pragma unroll
            for (int kst = 0; kst < 2; ++kst)
                vfrag[md][kst] = (u32x4){
                    pktrunc(accv[md][2*kst  ][0], accv[md][2*kst  ][1]),
                    pktrunc(accv[md][2*kst  ][2], accv[md][2*kst  ][3]),
                    pktrunc(accv[md][2*kst+1][0], accv[md][2*kst+1][1]),
                    pktrunc(accv[md][2*kst+1][2], accv[md][2*kst+1][3])};
    }
    // no barrier: qk store->read is same-wave (wave-private region)

    // ---- S^T = K @ Q^T (wave = head, wave-private LDS reads) ----
    f32x4 st[4][4];    // [mtKey][ntQuery]
    {
        bf16x8 kf[4], qf[4];
        #pragma unroll
        for (int mt = 0; mt < 4; ++mt)
            kf[mt] = *reinterpret_cast<const bf16x8*>(&qk[qkbase + (mt*16 + l15)*QKS + 32 + l4*8]);
        #pragma unroll
        for (int nt = 0; nt < 4; ++nt)
            qf[nt] = *reinterpret_cast<const bf16x8*>(&qk[qkbase + (nt*16 + l15)*QKS + l4*8]);
        #pragma unroll
        for (int mt = 0; mt < 4; ++mt)
            #pragma unroll
            for (int nt = 0; nt < 4; ++nt)
                st[mt][nt] = MFMA16(kf[mt], qf[nt], ((f32x4){0.f,0.f,0.f,0.f}));
    }
    __syncthreads();   // b3: all qk reads + hs reads done; os/h2 stores may clobber

    // ---- softmax over keys (in-lane 13 live + 2 shfl), pack P^T ----
    unsigned pk[4][4][2];   // [ntQuery][mtKey][pair]
    #pragma unroll
    for (int nq = 0; nq < 4; ++nq) {
        const int qc = (nq*16 + l15) < WT ? (nq*16 + l15) : 48;
        const float* bp = biasp + (wv*49 + qc)*64;
        float v[13];
        #pragma unroll
        for (int mk = 0; mk < 3; ++mk) {
            const float4 b4 = *reinterpret_cast<const float4*>(&bp[mk*16 + l4*4]);
            v[mk*4+0] = fmaf(st[mk][nq][0], SCALE, b4.x);
            v[mk*4+1] = fmaf(st[mk][nq][1], SCALE, b4.y);
            v[mk*4+2] = fmaf(st[mk][nq][2], SCALE, b4.z);
            v[mk*4+3] = fmaf(st[mk][nq][3], SCALE, b4.w);
        }
        v[12] = (l4 == 0) ? fmaf(st[3][nq][0], SCALE, bp[48]) : -1e30f;  // key 48
        float mx = v[0];
        #pragma unroll
        for (int t = 1; t < 13; ++t) mx = fmaxf(mx, v[t]);
        mx = fmaxf(mx, __shfl_xor(mx, 16));
        mx = fmaxf(mx, __shfl_xor(mx, 32));
        float sum = 0.f;
        #pragma unroll
        for (int t = 0; t < 13; ++t) { v[t] = __expf(v[t] - mx); sum += v[t]; }
        sum += __shfl_xor(sum, 16);
        sum += __shfl_xor(sum, 32);
        const float inv = 1.f / sum;
        #pragma unroll
        for (int mk = 0; mk < 3; ++mk) {
            pk[nq][mk][0] = pktrunc(v[mk*4+0]*inv, v[mk*4+1]*inv);
            pk[nq][mk][1] = pktrunc(v[mk*4+2]*inv, v[mk*4+3]*inv);
        }
        pk[nq][3][0] = pktrunc(v[12]*inv, 0.f);
        pk[nq][3][1] = 0u;
    }

    // ---- PV: o^T = V^T @ P^T — BOTH operands from registers ----
    {
        f32x4 oc[2][4];   // [mtDim][ntQuery]
        #pragma unroll
        for (int md = 0; md < 2; ++md)
            #pragma unroll
            for (int nq = 0; nq < 4; ++nq)
                oc[md][nq] = (f32x4){0.f,0.f,0.f,0.f};
        #pragma unroll
        for (int kst = 0; kst < 2; ++kst) {
            #pragma unroll
            for (int nq = 0; nq < 4; ++nq) {
                const bf16x8 bp8 = __builtin_bit_cast(bf16x8,
                    (u32x4){pk[nq][2*kst][0], pk[nq][2*kst][1], pk[nq][2*kst+1][0], pk[nq][2*kst+1][1]});
                #pragma unroll
                for (int md = 0; md < 2; ++md)
                    oc[md][nq] = MFMA16(__builtin_bit_cast(bf16x8, vfrag[md][kst]), bp8, oc[md][nq]);
            }
        }
        // os store (transpose back): os[query][inner]
        #pragma unroll
        for (int md = 0; md < 2; ++md)
            #pragma unroll
            for (int nq = 0; nq < 4; ++nq) {
                const unsigned lo = pktrunc(oc[md][nq][0], oc[md][nq][1]);
                const unsigned hi = pktrunc(oc[md][nq][2], oc[md][nq][3]);
                *reinterpret_cast<unsigned long long*>(
                    &os[(nq*16 + l15)*OSS + wv*32 + md*16 + l4*4]) =
                    ((unsigned long long)hi << 32) | lo;
            }
    }

    // ---- prefetches, placed AFTER PV so st/pk/vfrag are dead (no register peak) ----
    float xres[6][4];
    #pragma unroll
    for (int nt = 0; nt < 6; ++nt)
        #pragma unroll
        for (int rg = 0; rg < 4; ++rg) {
            const int tok = wv*16 + l4*4 + rg;
            const int tokc = tok < WT ? tok : 48;   // clamp: pad rows read real data, discarded later
            xres[nt][rg] = x[((size_t)b * NTOK + (size_t)(xr*7 + tokc/7) * IMG + (yr*7 + tokc%7)) * DIM + nt*16 + l15];
        }
    bf16x8 wofr[4][6];
    float bo6[6], g6[6], be6[6], b26[6], b1p[6];
    #pragma unroll
    for (int nt = 0; nt < 6; ++nt) {
        bo6[nt] = b_out[nt*16 + l15];
        g6[nt]  = ln2_g[nt*16 + l15];
        be6[nt] = ln2_b[nt*16 + l15];
        b26[nt] = b2[nt*16 + l15];
        #pragma unroll
        for (int kst = 0; kst < 4; ++kst)
            wofr[kst][nt] = ldfrag(woutb, nt*4 + kst, lane);
    }
    #pragma unroll
    for (int al = 0; al < 2; ++al)
        #pragma unroll
        for (int n3 = 0; n3 < 3; ++n3)
            b1p[al*3 + n3] = b1[al*192 + wv*48 + n3*16 + l15];
    __syncthreads();   // b4: os ready

    // ---- proj: os[64x128] @ Wout^T + b_out + xres -> yreg (no b5: h2 disjoint from os) ----
    float yreg[6][4];
    {
        bf16x8 afr[4];
        #pragma unroll
        for (int kst = 0; kst < 4; ++kst)
            afr[kst] = *reinterpret_cast<const bf16x8*>(&os[(wv*16 + l15)*OSS + kst*32 + l4*8]);
        #pragma unroll
        for (int nt = 0; nt < 6; ++nt) {
            f32x4 acc = (f32x4){0.f,0.f,0.f,0.f};
            #pragma unroll
            for (int kst = 0; kst < 4; ++kst)
                acc = MFMA16(afr[kst], wofr[kst][nt], acc);
            #pragma unroll
            for (int rg = 0; rg < 4; ++rg)
                yreg[nt][rg] = acc[rg] + bo6[nt] + xres[nt][rg];
        }
    }

    // ---- LN2 in-register (row over 16 l15-lanes x 6 nt) ----
    float mu4[4], rs4[4];
    #pragma unroll
    for (int rg = 0; rg < 4; ++rg) {
        float s = 0.f, s2 = 0.f;
        #pragma unroll
        for (int nt = 0; nt < 6; ++nt) { const float v = yreg[nt][rg]; s += v; s2 += v*v; }
        s  += __shfl_xor(s, 1);  s  += __shfl_xor(s, 2);  s  += __shfl_xor(s, 4);  s  += __shfl_xor(s, 8);
        s2 += __shfl_xor(s2, 1); s2 += __shfl_xor(s2, 2); s2 += __shfl_xor(s2, 4); s2 += __shfl_xor(s2, 8);
        const float m = s * (1.f/96.f);
        mu4[rg] = m;
        rs4[rg] = rsqrtf(s2 * (1.f/96.f) - m*m + 1e-5f);
    }
    #pragma unroll
    for (int nt = 0; nt < 6; ++nt)
        #pragma unroll
        for (int rg = 0; rg < 4; ++rg)
            h2[(wv*16 + l4*4 + rg)*104 + nt*16 + l15] =
                f2bf((yreg[nt][rg] - mu4[rg]) * rs4[rg] * g6[nt] + be6[nt]);
    __syncthreads();   // b6: h2 ready (os fully consumed; ts may overwrite it after this)

    // ---- FFN: GEMM1 halves (GELU -> ts) interleaved with GEMM2 k-partials ----
    f32x4 acc2[6];
    #pragma unroll
    for (int nt = 0; nt < 6; ++nt) acc2[nt] = (f32x4){0.f,0.f,0.f,0.f};

    #pragma unroll
    for (int al = 0; al < 2; ++al) {
        bf16x8 af[3][4];
        #pragma unroll
        for (int k3 = 0; k3 < 3; ++k3)
            #pragma unroll
            for (int mt = 0; mt < 4; ++mt)
                af[k3][mt] = *reinterpret_cast<const bf16x8*>(&h2[(mt*16 + l15)*104 + k3*32 + l4*8]);
        #pragma unroll
        for (int n3 = 0; n3 < 3; ++n3) {
            const int r1 = al*12 + wv*3 + n3;
            f32x4 a1[4];
            #pragma unroll
            for (int mt = 0; mt < 4; ++mt) a1[mt] = (f32x4){0.f,0.f,0.f,0.f};
            #pragma unroll
            for (int k3 = 0; k3 < 3; ++k3) {
                const bf16x8 bf = ldfrag(w1b, r1*3 + k3, lane);
                #pragma unroll
                for (int mt = 0; mt < 4; ++mt)
                    a1[mt] = MFMA16(af[k3][mt], bf, a1[mt]);
            }
            const float bb = b1p[al*3 + n3];
            #pragma unroll
            for (int mt = 0; mt < 4; ++mt)
                #pragma unroll
                for (int rg = 0; rg < 4; ++rg)
                    ts[(mt*16 + l4*4 + rg)*TSS + wv*48 + n3*16 + l15] = f2bf(gelu_f(a1[mt][rg] + bb));
        }
        __syncthreads();   // ts half ready
        bf16x8 at[6];
        #pragma unroll
        for (int kl = 0; kl < 6; ++kl)
            at[kl] = *reinterpret_cast<const bf16x8*>(&ts[(wv*16 + l15)*TSS + kl*32 + l4*8]);
        #pragma unroll
        for (int nt = 0; nt < 6; ++nt) {
            #pragma unroll
            for (int kl = 0; kl < 6; ++kl)
                acc2[nt] = MFMA16(at[kl], ldfrag(w2b, nt*12 + al*6 + kl, lane), acc2[nt]);
        }
        if (al == 0) __syncthreads();   // ts reads done before half-1 overwrites
    }

    // ---- final: y = gemm2 + b2 + yreg, single global write ----
    #pragma unroll
    for (int nt = 0; nt < 6; ++nt)
        #pragma unroll
        for (int rg = 0; rg < 4; ++rg) {
            const int tok = wv*16 + l4*4 + rg;
            if (tok < WT) {
                const size_t gi = ((size_t)b * NTOK + (size_t)(xr*7 + tok/7) * IMG + (yr*7 + tok%7)) * DIM + nt*16 + l15;
                y[gi] = acc2[nt][rg] + b26[nt] + yreg[nt][rg];
            }
        }
}

extern "C" void kernel_launch(void* const* d_in, const int* in_sizes, int n_in,
                              void* d_out, int out_size, void* d_ws, size_t ws_size,
                              hipStream_t stream) {
    const float* x     = (const float*)d_in[0];
    const float* w_qkv = (const float*)d_in[1];
    const float* w_out = (const float*)d_in[2];
    const float* b_out = (const float*)d_in[3];
    const float* rel_b = (const float*)d_in[4];
    const float* ln1_g = (const float*)d_in[5];
    const float* ln1_b = (const float*)d_in[6];
    const float* ln2_g = (const float*)d_in[7];
    const float* ln2_b = (const float*)d_in[8];
    const float* w1    = (const float*)d_in[9];
    const float* b1    = (const float*)d_in[10];
    const float* w2    = (const float*)d_in[11];
    const float* b2    = (const float*)d_in[12];
    float* y = (float*)d_out;
    char* ws = (char*)d_ws;

    prep_kernel<<<529, 256, 0, stream>>>(w_qkv, w_out, w1, w2, rel_b, ws);
    fused_kernel<<<NB * 32 * 32, 256, 0, stream>>>(x, ws, b_out, ln1_g, ln1_b,
                                                   ln2_g, ln2_b, b1, b2, y);
}